// Round 2
// baseline (1547.389 us; speedup 1.0000x reference)
//
#include <hip/hip_runtime.h>

#define NN 100000
#define EE 300000
#define DD 256
#define LL 5
#define GG 4096
#define DB 512
#define MPAD 100096   // 782*128

typedef __attribute__((ext_vector_type(4))) float f32x4;
typedef __attribute__((ext_vector_type(8))) short s16x8;

__device__ __forceinline__ ushort f2bf(float f) {
  unsigned u = __float_as_uint(f);
  return (ushort)((u + 0x7fffu + ((u >> 16) & 1u)) >> 16);
}

__device__ __forceinline__ void gload16(const void* g, void* l) {
  __builtin_amdgcn_global_load_lds((const __attribute__((address_space(1))) void*)g,
                                   (__attribute__((address_space(3))) void*)l, 16, 0, 0);
}

// ---------------- atom encoder: h[n,:] = sum_f atom_emb[f, x[n,f], :] (f32 -> d_out) ----
__global__ void k_atom(const int* __restrict__ x, const float* __restrict__ emb,
                       float* __restrict__ h) {
  int n = blockIdx.x * 4 + (threadIdx.x >> 6);
  if (n >= NN) return;
  int d = (threadIdx.x & 63) * 4;
  float ax = 0.f, ay = 0.f, az = 0.f, aw = 0.f;
#pragma unroll
  for (int f = 0; f < 9; ++f) {
    int v = x[n * 9 + f];
    const float4 t = *(const float4*)&emb[((size_t)(f * 120 + v)) * DD + d];
    ax += t.x; ay += t.y; az += t.z; aw += t.w;
  }
  *(float4*)&h[(size_t)n * DD + d] = make_float4(ax, ay, az, aw);
}

__global__ void k_vninit(const float* __restrict__ vn0, float* __restrict__ vn) {
  int i = blockIdx.x * blockDim.x + threadIdx.x;
  if (i < GG * DD) vn[i] = vn0[i & (DD - 1)];
}

__global__ void k_goff(const int* __restrict__ batch, int* __restrict__ goff) {
  int g = blockIdx.x * blockDim.x + threadIdx.x;
  if (g > GG) return;
  if (g == GG) { goff[GG] = NN; return; }
  int lo = 0, hi = NN;
  while (lo < hi) { int mid = (lo + hi) >> 1; if (batch[mid] < g) lo = mid + 1; else hi = mid; }
  goff[g] = lo;
}

__global__ void k_zero(int* __restrict__ p, int n) {
  int i = blockIdx.x * 256 + threadIdx.x;
  if (i < n) p[i] = 0;
}

__global__ void k_deg(const int* __restrict__ dst, int* __restrict__ deg) {
  int e = blockIdx.x * 256 + threadIdx.x;
  if (e < EE) atomicAdd(&deg[dst[e]], 1);
}

__global__ void k_scan(const int* __restrict__ deg, int* __restrict__ coff) {
  __shared__ int wsum[16];
  __shared__ int wpre[16];
  __shared__ int carry_s;
  int lane = threadIdx.x & 63, wid = threadIdx.x >> 6;
  if (threadIdx.x == 0) { coff[0] = 0; carry_s = 0; }
  __syncthreads();
  for (int base = 0; base < NN; base += 1024) {
    int i = base + threadIdx.x;
    int v = (i < NN) ? deg[i] : 0;
    int xv = v;
#pragma unroll
    for (int off = 1; off < 64; off <<= 1) {
      int y = __shfl_up(xv, off);
      if (lane >= off) xv += y;
    }
    if (lane == 63) wsum[wid] = xv;
    __syncthreads();
    if (wid == 0 && lane < 16) {
      int s = wsum[lane];
      int xx = s;
#pragma unroll
      for (int off = 1; off < 16; off <<= 1) {
        int y = __shfl_up(xx, off);
        if (lane >= off) xx += y;
      }
      wpre[lane] = xx - s;
      if (lane == 15) wsum[15] = xx;
    }
    __syncthreads();
    int val = xv + wpre[wid] + carry_s;
    if (i < NN) coff[i + 1] = val;
    int total = wsum[15];
    __syncthreads();
    if (threadIdx.x == 0) carry_s += total;
    __syncthreads();
  }
}

__global__ void k_eposinit(const int* __restrict__ coff, int* __restrict__ epos) {
  int n = blockIdx.x * 256 + threadIdx.x;
  if (n < NN) epos[n] = coff[n];
}

__global__ void k_scatter(const int* __restrict__ dst, int* __restrict__ epos,
                          int* __restrict__ eid) {
  int e = blockIdx.x * 256 + threadIdx.x;
  if (e < EE) { int p = atomicAdd(&epos[dst[e]], 1); eid[p] = e; }
}

__global__ void k_sort(const int* __restrict__ coff, int* __restrict__ eid) {
  int n = blockIdx.x * 256 + threadIdx.x;
  if (n >= NN) return;
  int s = coff[n], t = coff[n + 1];
  for (int i = s + 1; i < t; ++i) {
    int key = eid[i]; int j = i - 1;
    while (j >= s && eid[j] > key) { eid[j + 1] = eid[j]; --j; }
    eid[j + 1] = key;
  }
}

// ---------------- weight transpose + bf16: in [L][K][N] f32 -> out [L][N][K] bf16 -------
__global__ void k_wt(const float* __restrict__ in, ushort* __restrict__ out, int K, int N) {
  __shared__ float t[16][17];
  int l = blockIdx.z;
  int kb = blockIdx.x * 16, nb = blockIdx.y * 16;
  int tx = threadIdx.x & 15, ty = threadIdx.x >> 4;
  t[ty][tx] = in[(size_t)l * K * N + (size_t)(kb + ty) * N + nb + tx];
  __syncthreads();
  out[(size_t)l * N * K + (size_t)(nb + ty) * K + kb + tx] = f2bf(t[tx][ty]);
}

// ---------------- h += vn[batch] (in-place, f32) + pool: vtemp[g]=sum(h_post)+vn (bf16) --
__global__ void k_vnadd_pool(float* __restrict__ h, const float* __restrict__ vn,
                             ushort* __restrict__ vtempb, const int* __restrict__ goff,
                             int writePool) {
  int g = blockIdx.x * 4 + (threadIdx.x >> 6);
  if (g >= GG) return;
  int d = (threadIdx.x & 63) * 4;
  float4 v = *(const float4*)&vn[(size_t)g * DD + d];
  float ax = v.x, ay = v.y, az = v.z, aw = v.w;
  int r0 = goff[g], r1 = goff[g + 1];
  for (int r = r0; r < r1; ++r) {
    float4 hv = *(float4*)&h[(size_t)r * DD + d];
    hv.x += v.x; hv.y += v.y; hv.z += v.z; hv.w += v.w;
    *(float4*)&h[(size_t)r * DD + d] = hv;
    ax += hv.x; ay += hv.y; az += hv.z; aw += hv.w;
  }
  if (writePool) {
    ushort4 o; o.x = f2bf(ax); o.y = f2bf(ay); o.z = f2bf(az); o.w = f2bf(aw);
    *(ushort4*)&vtempb[(size_t)g * DD + d] = o;
  }
}

// ---------------- aggregate -> t bf16: t[n] = (1+eps)h[n] + sum relu(h[src]+bond(e)) ----
__global__ void k_aggr(const float* __restrict__ h, ushort* __restrict__ tb,
                       const int* __restrict__ srcs, const int* __restrict__ eid,
                       const int* __restrict__ coff, const int* __restrict__ eattr,
                       const float* __restrict__ bond, const float* __restrict__ epsp, int l) {
  int n = blockIdx.x * 4 + (threadIdx.x >> 6);
  if (n >= NN) return;
  int d = (threadIdx.x & 63) * 4;
  float ax = 0.f, ay = 0.f, az = 0.f, aw = 0.f;
  int s0 = coff[n], s1 = coff[n + 1];
  for (int idx = s0; idx < s1; ++idx) {
    int e = eid[idx];
    int s = srcs[e];
    int a0 = eattr[e * 3 + 0], a1 = eattr[e * 3 + 1], a2 = eattr[e * 3 + 2];
    const float4 hs = *(const float4*)&h[(size_t)s * DD + d];
    const float4 e0 = *(const float4*)&bond[(size_t)(0 * 6 + a0) * DD + d];
    const float4 e1 = *(const float4*)&bond[(size_t)(1 * 6 + a1) * DD + d];
    const float4 e2 = *(const float4*)&bond[(size_t)(2 * 6 + a2) * DD + d];
    ax += fmaxf(hs.x + e0.x + e1.x + e2.x, 0.f);
    ay += fmaxf(hs.y + e0.y + e1.y + e2.y, 0.f);
    az += fmaxf(hs.z + e0.z + e1.z + e2.z, 0.f);
    aw += fmaxf(hs.w + e0.w + e1.w + e2.w, 0.f);
  }
  float ep = 1.f + epsp[l];
  const float4 hn = *(const float4*)&h[(size_t)n * DD + d];
  ushort4 o;
  o.x = f2bf(ep * hn.x + ax); o.y = f2bf(ep * hn.y + ay);
  o.z = f2bf(ep * hn.z + az); o.w = f2bf(ep * hn.w + aw);
  *(ushort4*)&tb[(size_t)n * DD + d] = o;
}

// ---------------- bf16 MFMA GEMM, m97-style 128x128 tile, fused bias/BN(/relu) ----------
// A [>=Mtiles*128][K] bf16 row-major, BT [N][K] bf16 row-major.
// C[row][col] = epi(sum_k A[row][k]*BT[col][k]); stores guarded row<M.
__global__ __launch_bounds__(256) void k_mfma_gemm(
    const ushort* __restrict__ A, int M, int K,
    const ushort* __restrict__ BT, int N,
    void* __restrict__ Cv, int outBf16, int doRelu,
    const float* __restrict__ bias, const float* __restrict__ bn) {
  __shared__ ushort Asm[128 * 32];
  __shared__ ushort Bsm[128 * 32];
  const int tid = threadIdx.x;
  const int lane = tid & 63;
  const int w = tid >> 6;
  const int rowBase = blockIdx.x * 128;
  const int colBase = blockIdx.y * 128;
  const int wrow = (w >> 1) * 64, wcol = (w & 1) * 64;
  const int r16 = lane & 15, kgrp = lane >> 4;

  f32x4 acc[4][4];
#pragma unroll
  for (int m = 0; m < 4; ++m)
#pragma unroll
    for (int n = 0; n < 4; ++n) acc[m][n] = (f32x4)0.f;

  // staging: 512 16B chunks per tile; chunk c -> LDS offset c*16 (linear, wave-uniform+lane*16)
  // LDS slot (r, s) holds global k-group (s ^ ((r>>1)&3))  [XOR swizzle, 2-way max conflict]
  const int ca0 = tid, ca1 = tid + 256;
  const int ra0 = ca0 >> 2, ka0 = (ca0 & 3) ^ ((ra0 >> 1) & 3);
  const int ra1 = ca1 >> 2, ka1 = (ca1 & 3) ^ ((ra1 >> 1) & 3);
  const ushort* Ap0 = A + (size_t)(rowBase + ra0) * K + ka0 * 8;
  const ushort* Ap1 = A + (size_t)(rowBase + ra1) * K + ka1 * 8;
  const ushort* Bp0 = BT + (size_t)(colBase + ra0) * K + ka0 * 8;
  const ushort* Bp1 = BT + (size_t)(colBase + ra1) * K + ka1 * 8;
  char* dA0 = (char*)Asm + ca0 * 16;
  char* dA1 = (char*)Asm + ca1 * 16;
  char* dB0 = (char*)Bsm + ca0 * 16;
  char* dB1 = (char*)Bsm + ca1 * 16;

  int aoff[4], boff[4];
#pragma unroll
  for (int m = 0; m < 4; ++m) {
    int row = wrow + m * 16 + r16;
    aoff[m] = row * 64 + ((kgrp ^ ((row >> 1) & 3)) << 4);
    int col = wcol + m * 16 + r16;
    boff[m] = col * 64 + ((kgrp ^ ((col >> 1) & 3)) << 4);
  }

  for (int k0 = 0; k0 < K; k0 += 32) {
    gload16(Ap0 + k0, dA0);
    gload16(Ap1 + k0, dA1);
    gload16(Bp0 + k0, dB0);
    gload16(Bp1 + k0, dB1);
    __syncthreads();   // compiler drains vmcnt before barrier
    s16x8 a[4], b[4];
#pragma unroll
    for (int m = 0; m < 4; ++m) a[m] = *(const s16x8*)((const char*)Asm + aoff[m]);
#pragma unroll
    for (int n = 0; n < 4; ++n) b[n] = *(const s16x8*)((const char*)Bsm + boff[n]);
#pragma unroll
    for (int m = 0; m < 4; ++m)
#pragma unroll
      for (int n = 0; n < 4; ++n)
        acc[m][n] = __builtin_amdgcn_mfma_f32_16x16x32_bf16(a[m], b[n], acc[m][n], 0, 0, 0);
    __syncthreads();
  }

  float alpha[4], beta[4];
#pragma unroll
  for (int n = 0; n < 4; ++n) {
    int col = colBase + wcol + n * 16 + r16;
    float g = bn[col], bb = bn[N + col], mm = bn[2 * N + col], vv = bn[3 * N + col];
    float s = g * rsqrtf(vv + 1e-5f);
    alpha[n] = s; beta[n] = fmaf(bias[col] - mm, s, bb);
  }
#pragma unroll
  for (int m = 0; m < 4; ++m) {
#pragma unroll
    for (int r = 0; r < 4; ++r) {
      int row = rowBase + wrow + m * 16 + kgrp * 4 + r;
      if (row < M) {
#pragma unroll
        for (int n = 0; n < 4; ++n) {
          int col = colBase + wcol + n * 16 + r16;
          float v = fmaf(acc[m][n][r], alpha[n], beta[n]);
          if (doRelu) v = fmaxf(v, 0.f);
          if (outBf16) ((ushort*)Cv)[(size_t)row * N + col] = f2bf(v);
          else         ((float*)Cv)[(size_t)row * N + col] = v;
        }
      }
    }
  }
}

extern "C" void kernel_launch(void* const* d_in, const int* in_sizes, int n_in,
                              void* d_out, int out_size, void* d_ws, size_t ws_size,
                              hipStream_t stream) {
  const int*   x     = (const int*)d_in[0];
  const int*   ei    = (const int*)d_in[1];
  const int*   ea    = (const int*)d_in[2];
  const int*   batch = (const int*)d_in[3];
  const float* atomE = (const float*)d_in[4];
  const float* bondE = (const float*)d_in[5];
  const float* vn0   = (const float*)d_in[6];
  const float* eps   = (const float*)d_in[7];
  const float* cW1   = (const float*)d_in[8];
  const float* cb1   = (const float*)d_in[9];
  const float* cbn1  = (const float*)d_in[10];
  const float* cW2   = (const float*)d_in[11];
  const float* cb2   = (const float*)d_in[12];
  const float* nbn   = (const float*)d_in[13];
  const float* vW1   = (const float*)d_in[14];
  const float* vb1   = (const float*)d_in[15];
  const float* vbn1  = (const float*)d_in[16];
  const float* vW2   = (const float*)d_in[17];
  const float* vb2   = (const float*)d_in[18];
  const float* vbn2  = (const float*)d_in[19];
  (void)in_sizes; (void)n_in; (void)out_size; (void)ws_size;

  char* wsp = (char*)d_ws;
  size_t o = 0;
  auto alloc = [&](size_t bytes) -> char* {
    char* p = wsp + o; o += (bytes + 255) & ~(size_t)255; return p;
  };
  ushort* tbuf  = (ushort*)alloc((size_t)MPAD * DD * 2);   // 51.2 MB
  ushort* c1b   = (ushort*)alloc((size_t)MPAD * DB * 2);   // 102.5 MB
  float*  vn    = (float*) alloc((size_t)GG * DD * 4);
  ushort* vtmpb = (ushort*)alloc((size_t)GG * DD * 2);
  ushort* ub    = (ushort*)alloc((size_t)GG * DD * 2);
  ushort* bw1   = (ushort*)alloc((size_t)LL * DB * DD * 2);
  ushort* bw2   = (ushort*)alloc((size_t)LL * DD * DB * 2);
  ushort* bvw1  = (ushort*)alloc((size_t)(LL - 1) * DD * DD * 2);
  ushort* bvw2  = (ushort*)alloc((size_t)(LL - 1) * DD * DD * 2);
  int* coff = (int*)alloc((size_t)(NN + 1) * 4);
  int* deg  = (int*)alloc((size_t)NN * 4);
  int* epos = (int*)alloc((size_t)NN * 4);
  int* eid  = (int*)alloc((size_t)EE * 4);
  int* goff = (int*)alloc((size_t)(GG + 1) * 4);
  // total ~167 MB

  const int* srcs = ei;
  const int* dsts = ei + EE;
  float* h = (float*)d_out;   // h-stream lives in d_out across all layers

  // ---- one-time per call ----
  k_atom<<<(NN + 3) / 4, 256, 0, stream>>>(x, atomE, h);
  k_vninit<<<(GG * DD + 255) / 256, 256, 0, stream>>>(vn0, vn);
  k_goff<<<(GG + 256) / 256, 256, 0, stream>>>(batch, goff);
  k_zero<<<(NN + 255) / 256, 256, 0, stream>>>(deg, NN);
  k_deg<<<(EE + 255) / 256, 256, 0, stream>>>(dsts, deg);
  k_scan<<<1, 1024, 0, stream>>>(deg, coff);
  k_eposinit<<<(NN + 255) / 256, 256, 0, stream>>>(coff, epos);
  k_scatter<<<(EE + 255) / 256, 256, 0, stream>>>(dsts, epos, eid);
  k_sort<<<(NN + 255) / 256, 256, 0, stream>>>(coff, eid);
  k_wt<<<dim3(DD / 16, DB / 16, LL), 256, 0, stream>>>(cW1, bw1, DD, DB);
  k_wt<<<dim3(DB / 16, DD / 16, LL), 256, 0, stream>>>(cW2, bw2, DB, DD);
  k_wt<<<dim3(DD / 16, DD / 16, LL - 1), 256, 0, stream>>>(vW1, bvw1, DD, DD);
  k_wt<<<dim3(DD / 16, DD / 16, LL - 1), 256, 0, stream>>>(vW2, bvw2, DD, DD);

  for (int l = 0; l < LL; ++l) {
    int writePool = (l < LL - 1) ? 1 : 0;
    k_vnadd_pool<<<(GG + 3) / 4, 256, 0, stream>>>(h, vn, vtmpb, goff, writePool);
    k_aggr<<<(NN + 3) / 4, 256, 0, stream>>>(h, tbuf, srcs, eid, coff, ea,
                                             bondE + (size_t)l * 3 * 6 * DD, eps, l);
    k_mfma_gemm<<<dim3(MPAD / 128, DB / 128), 256, 0, stream>>>(
        tbuf, NN, DD, bw1 + (size_t)l * DB * DD, DB,
        c1b, 1, 1, cb1 + (size_t)l * DB, cbn1 + (size_t)l * 4 * DB);
    k_mfma_gemm<<<dim3(MPAD / 128, DD / 128), 256, 0, stream>>>(
        c1b, NN, DB, bw2 + (size_t)l * DD * DB, DD,
        h, 0, (l < LL - 1) ? 1 : 0, cb2 + (size_t)l * DD, nbn + (size_t)l * 4 * DD);
    if (writePool) {
      k_mfma_gemm<<<dim3(GG / 128, DD / 128), 256, 0, stream>>>(
          vtmpb, GG, DD, bvw1 + (size_t)l * DD * DD, DD,
          ub, 1, 1, vb1 + (size_t)l * DD, vbn1 + (size_t)l * 4 * DD);
      k_mfma_gemm<<<dim3(GG / 128, DD / 128), 256, 0, stream>>>(
          ub, GG, DD, bvw2 + (size_t)l * DD * DD, DD,
          vn, 0, 1, vb2 + (size_t)l * DD, vbn2 + (size_t)l * 4 * DD);
    }
  }
}

// Round 3
// 1371.177 us; speedup vs baseline: 1.1285x; 1.1285x over previous
//
#include <hip/hip_runtime.h>

#define NN 100000
#define EE 300000
#define DD 256
#define LL 5
#define GG 4096
#define DB 512
#define MPAD 100096   // 782*128

typedef __attribute__((ext_vector_type(4))) float f32x4;
typedef __attribute__((ext_vector_type(8))) short s16x8;

__device__ __forceinline__ ushort f2bf(float f) {
  unsigned u = __float_as_uint(f);
  return (ushort)((u + 0x7fffu + ((u >> 16) & 1u)) >> 16);
}
__device__ __forceinline__ float b2f(ushort u) {
  return __uint_as_float(((unsigned)u) << 16);
}

__device__ __forceinline__ void gload16(const void* g, void* l) {
  __builtin_amdgcn_global_load_lds((const __attribute__((address_space(1))) void*)g,
                                   (__attribute__((address_space(3))) void*)l, 16, 0, 0);
}

// ---------------- atom encoder: hb[n,:] = bf16( sum_f atom_emb[f, x[n,f], :] ) ----------
__global__ void k_atom(const int* __restrict__ x, const float* __restrict__ emb,
                       ushort* __restrict__ hb) {
  int n = blockIdx.x * 4 + (threadIdx.x >> 6);
  if (n >= NN) return;
  int d = (threadIdx.x & 63) * 4;
  float ax = 0.f, ay = 0.f, az = 0.f, aw = 0.f;
#pragma unroll
  for (int f = 0; f < 9; ++f) {
    int v = x[n * 9 + f];
    const float4 t = *(const float4*)&emb[((size_t)(f * 120 + v)) * DD + d];
    ax += t.x; ay += t.y; az += t.z; aw += t.w;
  }
  ushort4 o; o.x = f2bf(ax); o.y = f2bf(ay); o.z = f2bf(az); o.w = f2bf(aw);
  *(ushort4*)&hb[(size_t)n * DD + d] = o;
}

__global__ void k_vninit(const float* __restrict__ vn0, float* __restrict__ vn) {
  int i = blockIdx.x * blockDim.x + threadIdx.x;
  if (i < GG * DD) vn[i] = vn0[i & (DD - 1)];
}

__global__ void k_goff(const int* __restrict__ batch, int* __restrict__ goff) {
  int g = blockIdx.x * blockDim.x + threadIdx.x;
  if (g > GG) return;
  if (g == GG) { goff[GG] = NN; return; }
  int lo = 0, hi = NN;
  while (lo < hi) { int mid = (lo + hi) >> 1; if (batch[mid] < g) lo = mid + 1; else hi = mid; }
  goff[g] = lo;
}

__global__ void k_zero(int* __restrict__ p, int n) {
  int i = blockIdx.x * 256 + threadIdx.x;
  if (i < n) p[i] = 0;
}

__global__ void k_deg(const int* __restrict__ dst, int* __restrict__ deg) {
  int e = blockIdx.x * 256 + threadIdx.x;
  if (e < EE) atomicAdd(&deg[dst[e]], 1);
}

// ---------------- hierarchical scan: coff = exclusive prefix of deg, +1 shifted ---------
__global__ void k_scan1(const int* __restrict__ deg, int* __restrict__ coff,
                        int* __restrict__ bsum) {
  __shared__ int wsum[16];
  __shared__ int wpre[16];
  int lane = threadIdx.x & 63, wid = threadIdx.x >> 6;
  int i = blockIdx.x * 1024 + threadIdx.x;
  int v = (i < NN) ? deg[i] : 0;
  int xv = v;
#pragma unroll
  for (int off = 1; off < 64; off <<= 1) {
    int y = __shfl_up(xv, off);
    if (lane >= off) xv += y;
  }
  if (lane == 63) wsum[wid] = xv;
  __syncthreads();
  if (wid == 0 && lane < 16) {
    int s = wsum[lane];
    int xx = s;
#pragma unroll
    for (int off = 1; off < 16; off <<= 1) {
      int y = __shfl_up(xx, off);
      if (lane >= off) xx += y;
    }
    wpre[lane] = xx - s;
  }
  __syncthreads();
  int val = xv + wpre[wid];
  if (i < NN) coff[i + 1] = val;
  if (threadIdx.x == 1023) bsum[blockIdx.x] = val;
}

__global__ void k_scan2(int* __restrict__ bsum, int nb) {   // 1 block, 128 threads
  __shared__ int ws[2];
  int t = threadIdx.x, lane = t & 63, wid = t >> 6;
  int v = (t < nb) ? bsum[t] : 0;
  int xv = v;
#pragma unroll
  for (int off = 1; off < 64; off <<= 1) {
    int y = __shfl_up(xv, off);
    if (lane >= off) xv += y;
  }
  if (lane == 63) ws[wid] = xv;
  __syncthreads();
  int incl = xv + ((wid == 1) ? ws[0] : 0);
  if (t < nb) bsum[t] = incl - v;   // exclusive prefix
}

__global__ void k_scan3(int* __restrict__ coff, const int* __restrict__ bpre) {
  int i = blockIdx.x * 1024 + threadIdx.x;
  if (i == 0) coff[0] = 0;
  if (i < NN) coff[i + 1] += bpre[i >> 10];
}

__global__ void k_eposinit(const int* __restrict__ coff, int* __restrict__ epos) {
  int n = blockIdx.x * 256 + threadIdx.x;
  if (n < NN) epos[n] = coff[n];
}

__global__ void k_scatter(const int* __restrict__ dst, int* __restrict__ epos,
                          int* __restrict__ eid) {
  int e = blockIdx.x * 256 + threadIdx.x;
  if (e < EE) { int p = atomicAdd(&epos[dst[e]], 1); eid[p] = e; }
}

__global__ void k_sort(const int* __restrict__ coff, int* __restrict__ eid) {
  int n = blockIdx.x * 256 + threadIdx.x;
  if (n >= NN) return;
  int s = coff[n], t = coff[n + 1];
  for (int i = s + 1; i < t; ++i) {
    int key = eid[i]; int j = i - 1;
    while (j >= s && eid[j] > key) { eid[j + 1] = eid[j]; --j; }
    eid[j + 1] = key;
  }
}

// ---------------- weight transpose + bf16: [L][K][N] f32 -> [L][N][K] bf16 --------------
__global__ void k_wt(const float* __restrict__ in, ushort* __restrict__ out, int K, int N) {
  __shared__ float t[16][17];
  int l = blockIdx.z;
  int kb = blockIdx.x * 16, nb = blockIdx.y * 16;
  int tx = threadIdx.x & 15, ty = threadIdx.x >> 4;
  t[ty][tx] = in[(size_t)l * K * N + (size_t)(kb + ty) * N + nb + tx];
  __syncthreads();
  out[(size_t)l * N * K + (size_t)(nb + ty) * K + kb + tx] = f2bf(t[tx][ty]);
}

// ---------------- prep: hv[n]=hb[n]+vn[g] (bf16); pool: vtemp[g]=sum(hv)+vn[g] ----------
__global__ void k_prep(const ushort* __restrict__ hb, const float* __restrict__ vn,
                       ushort* __restrict__ hvb, ushort* __restrict__ vtempb,
                       const int* __restrict__ goff, int writePool) {
  int g = blockIdx.x * 4 + (threadIdx.x >> 6);
  if (g >= GG) return;
  int d = (threadIdx.x & 63) * 4;
  float4 v = *(const float4*)&vn[(size_t)g * DD + d];
  float ax = v.x, ay = v.y, az = v.z, aw = v.w;   // vtemp = sum(hv) + vn
  int r0 = goff[g], r1 = goff[g + 1];
  for (int r = r0; r < r1; ++r) {
    ushort4 hu = *(const ushort4*)&hb[(size_t)r * DD + d];
    float h0 = b2f(hu.x) + v.x, h1 = b2f(hu.y) + v.y;
    float h2 = b2f(hu.z) + v.z, h3 = b2f(hu.w) + v.w;
    ushort4 o; o.x = f2bf(h0); o.y = f2bf(h1); o.z = f2bf(h2); o.w = f2bf(h3);
    *(ushort4*)&hvb[(size_t)r * DD + d] = o;
    ax += h0; ay += h1; az += h2; aw += h3;
  }
  if (writePool) {
    ushort4 o; o.x = f2bf(ax); o.y = f2bf(ay); o.z = f2bf(az); o.w = f2bf(aw);
    *(ushort4*)&vtempb[(size_t)g * DD + d] = o;
  }
}

// ---------------- aggregate: t[n] = (1+eps)hv[n] + sum relu(hv[src]+bond(e)) (bf16) -----
__global__ void k_aggr(const ushort* __restrict__ hvb, ushort* __restrict__ tb,
                       const int* __restrict__ srcs, const int* __restrict__ eid,
                       const int* __restrict__ coff, const int* __restrict__ eattr,
                       const float* __restrict__ bond, const float* __restrict__ epsp, int l) {
  int n = blockIdx.x * 4 + (threadIdx.x >> 6);
  if (n >= NN) return;
  int d = (threadIdx.x & 63) * 4;
  float ax = 0.f, ay = 0.f, az = 0.f, aw = 0.f;
  int s0 = coff[n], s1 = coff[n + 1];
  for (int idx = s0; idx < s1; ++idx) {
    int e = eid[idx];
    int s = srcs[e];
    int a0 = eattr[e * 3 + 0], a1 = eattr[e * 3 + 1], a2 = eattr[e * 3 + 2];
    const ushort4 hs = *(const ushort4*)&hvb[(size_t)s * DD + d];
    const float4 e0 = *(const float4*)&bond[(size_t)(0 * 6 + a0) * DD + d];
    const float4 e1 = *(const float4*)&bond[(size_t)(1 * 6 + a1) * DD + d];
    const float4 e2 = *(const float4*)&bond[(size_t)(2 * 6 + a2) * DD + d];
    ax += fmaxf(b2f(hs.x) + e0.x + e1.x + e2.x, 0.f);
    ay += fmaxf(b2f(hs.y) + e0.y + e1.y + e2.y, 0.f);
    az += fmaxf(b2f(hs.z) + e0.z + e1.z + e2.z, 0.f);
    aw += fmaxf(b2f(hs.w) + e0.w + e1.w + e2.w, 0.f);
  }
  float ep = 1.f + epsp[l];
  const ushort4 hn = *(const ushort4*)&hvb[(size_t)n * DD + d];
  ushort4 o;
  o.x = f2bf(ep * b2f(hn.x) + ax); o.y = f2bf(ep * b2f(hn.y) + ay);
  o.z = f2bf(ep * b2f(hn.z) + az); o.w = f2bf(ep * b2f(hn.w) + aw);
  *(ushort4*)&tb[(size_t)n * DD + d] = o;
}

// ---------------- bf16 MFMA GEMM, 128x128 tile, 2-phase dbuf, fused bias/BN(/relu) ------
__global__ __launch_bounds__(256) void k_mfma_gemm(
    const ushort* __restrict__ A, int M, int K,
    const ushort* __restrict__ BT, int N,
    void* __restrict__ Cv, int outBf16, int doRelu,
    const float* __restrict__ bias, const float* __restrict__ bn) {
  __shared__ ushort Asm[2][128 * 32];
  __shared__ ushort Bsm[2][128 * 32];
  const int tid = threadIdx.x;
  const int lane = tid & 63;
  const int w = tid >> 6;
  const int rowBase = blockIdx.x * 128;
  const int colBase = blockIdx.y * 128;
  const int wrow = (w >> 1) * 64, wcol = (w & 1) * 64;
  const int r16 = lane & 15, kgrp = lane >> 4;

  f32x4 acc[4][4];
#pragma unroll
  for (int m = 0; m < 4; ++m)
#pragma unroll
    for (int n = 0; n < 4; ++n) acc[m][n] = (f32x4)0.f;

  // chunk c -> LDS offset c*16 (linear); LDS slot (r,s) holds global k-group s^((r>>1)&3)
  const int ca0 = tid, ca1 = tid + 256;
  const int ra0 = ca0 >> 2, ka0 = (ca0 & 3) ^ ((ra0 >> 1) & 3);
  const int ra1 = ca1 >> 2, ka1 = (ca1 & 3) ^ ((ra1 >> 1) & 3);
  const ushort* Ap0 = A + (size_t)(rowBase + ra0) * K + ka0 * 8;
  const ushort* Ap1 = A + (size_t)(rowBase + ra1) * K + ka1 * 8;
  const ushort* Bp0 = BT + (size_t)(colBase + ra0) * K + ka0 * 8;
  const ushort* Bp1 = BT + (size_t)(colBase + ra1) * K + ka1 * 8;

  int aoff[4], boff[4];
#pragma unroll
  for (int m = 0; m < 4; ++m) {
    int row = wrow + m * 16 + r16;
    aoff[m] = row * 64 + ((kgrp ^ ((row >> 1) & 3)) << 4);
    int col = wcol + m * 16 + r16;
    boff[m] = col * 64 + ((kgrp ^ ((col >> 1) & 3)) << 4);
  }

  const int nk = K >> 5;
  // prologue: stage K-step 0 into buf 0
  gload16(Ap0, (char*)Asm + ca0 * 16);
  gload16(Ap1, (char*)Asm + ca1 * 16);
  gload16(Bp0, (char*)Bsm + ca0 * 16);
  gload16(Bp1, (char*)Bsm + ca1 * 16);
  __syncthreads();

  int cur = 0;
  for (int t = 0; t < nk; ++t) {
    int nxt = cur ^ 1;
    if (t + 1 < nk) {
      int ko = (t + 1) << 5;
      gload16(Ap0 + ko, (char*)Asm + nxt * 8192 + ca0 * 16);
      gload16(Ap1 + ko, (char*)Asm + nxt * 8192 + ca1 * 16);
      gload16(Bp0 + ko, (char*)Bsm + nxt * 8192 + ca0 * 16);
      gload16(Bp1 + ko, (char*)Bsm + nxt * 8192 + ca1 * 16);
    }
    const char* cA = (const char*)Asm + cur * 8192;
    const char* cB = (const char*)Bsm + cur * 8192;
    s16x8 a[4], b[4];
#pragma unroll
    for (int m = 0; m < 4; ++m) a[m] = *(const s16x8*)(cA + aoff[m]);
#pragma unroll
    for (int n = 0; n < 4; ++n) b[n] = *(const s16x8*)(cB + boff[n]);
#pragma unroll
    for (int m = 0; m < 4; ++m)
#pragma unroll
      for (int n = 0; n < 4; ++n)
        acc[m][n] = __builtin_amdgcn_mfma_f32_16x16x32_bf16(a[m], b[n], acc[m][n], 0, 0, 0);
    __syncthreads();   // drains this iter's prefetch; protects cur buf reuse
    cur = nxt;
  }

  float alpha[4], beta[4];
#pragma unroll
  for (int n = 0; n < 4; ++n) {
    int col = colBase + wcol + n * 16 + r16;
    float g = bn[col], bb = bn[N + col], mm = bn[2 * N + col], vv = bn[3 * N + col];
    float s = g * rsqrtf(vv + 1e-5f);
    alpha[n] = s; beta[n] = fmaf(bias[col] - mm, s, bb);
  }
#pragma unroll
  for (int m = 0; m < 4; ++m) {
#pragma unroll
    for (int r = 0; r < 4; ++r) {
      int row = rowBase + wrow + m * 16 + kgrp * 4 + r;
      if (row < M) {
#pragma unroll
        for (int n = 0; n < 4; ++n) {
          int col = colBase + wcol + n * 16 + r16;
          float v = fmaf(acc[m][n][r], alpha[n], beta[n]);
          if (doRelu) v = fmaxf(v, 0.f);
          if (outBf16) ((ushort*)Cv)[(size_t)row * N + col] = f2bf(v);
          else         ((float*)Cv)[(size_t)row * N + col] = v;
        }
      }
    }
  }
}

extern "C" void kernel_launch(void* const* d_in, const int* in_sizes, int n_in,
                              void* d_out, int out_size, void* d_ws, size_t ws_size,
                              hipStream_t stream) {
  const int*   x     = (const int*)d_in[0];
  const int*   ei    = (const int*)d_in[1];
  const int*   ea    = (const int*)d_in[2];
  const int*   batch = (const int*)d_in[3];
  const float* atomE = (const float*)d_in[4];
  const float* bondE = (const float*)d_in[5];
  const float* vn0   = (const float*)d_in[6];
  const float* eps   = (const float*)d_in[7];
  const float* cW1   = (const float*)d_in[8];
  const float* cb1   = (const float*)d_in[9];
  const float* cbn1  = (const float*)d_in[10];
  const float* cW2   = (const float*)d_in[11];
  const float* cb2   = (const float*)d_in[12];
  const float* nbn   = (const float*)d_in[13];
  const float* vW1   = (const float*)d_in[14];
  const float* vb1   = (const float*)d_in[15];
  const float* vbn1  = (const float*)d_in[16];
  const float* vW2   = (const float*)d_in[17];
  const float* vb2   = (const float*)d_in[18];
  const float* vbn2  = (const float*)d_in[19];
  (void)in_sizes; (void)n_in; (void)out_size; (void)ws_size;

  char* wsp = (char*)d_ws;
  size_t o = 0;
  auto alloc = [&](size_t bytes) -> char* {
    char* p = wsp + o; o += (bytes + 255) & ~(size_t)255; return p;
  };
  ushort* tbuf  = (ushort*)alloc((size_t)MPAD * DD * 2);   // 51.2 MB
  ushort* c1b   = (ushort*)alloc((size_t)MPAD * DB * 2);   // 102.5 MB
  ushort* hb    = (ushort*)alloc((size_t)NN * DD * 2);     // 51.2 MB
  float*  vn    = (float*) alloc((size_t)GG * DD * 4);
  ushort* vtmpb = (ushort*)alloc((size_t)GG * DD * 2);
  ushort* ub    = (ushort*)alloc((size_t)GG * DD * 2);
  ushort* bw1   = (ushort*)alloc((size_t)LL * DB * DD * 2);
  ushort* bw2   = (ushort*)alloc((size_t)LL * DD * DB * 2);
  ushort* bvw1  = (ushort*)alloc((size_t)(LL - 1) * DD * DD * 2);
  ushort* bvw2  = (ushort*)alloc((size_t)(LL - 1) * DD * DD * 2);
  int* coff = (int*)alloc((size_t)(NN + 1) * 4);
  int* deg  = (int*)alloc((size_t)NN * 4);
  int* epos = (int*)alloc((size_t)NN * 4);
  int* eid  = (int*)alloc((size_t)EE * 4);
  int* goff = (int*)alloc((size_t)(GG + 1) * 4);
  int* bsum = (int*)alloc((size_t)128 * 4);
  // total ~222 MB

  const int* srcs = ei;
  const int* dsts = ei + EE;
  // hv (bf16) lives in d_out's low half; freed before layer-4 GEMM2 writes f32 output
  ushort* hvb = (ushort*)d_out;

  // ---- one-time per call ----
  k_atom<<<(NN + 3) / 4, 256, 0, stream>>>(x, atomE, hb);
  k_vninit<<<(GG * DD + 255) / 256, 256, 0, stream>>>(vn0, vn);
  k_goff<<<(GG + 256) / 256, 256, 0, stream>>>(batch, goff);
  k_zero<<<(NN + 255) / 256, 256, 0, stream>>>(deg, NN);
  k_deg<<<(EE + 255) / 256, 256, 0, stream>>>(dsts, deg);
  {
    int nb = (NN + 1023) / 1024;   // 98
    k_scan1<<<nb, 1024, 0, stream>>>(deg, coff, bsum);
    k_scan2<<<1, 128, 0, stream>>>(bsum, nb);
    k_scan3<<<nb, 1024, 0, stream>>>(coff, bsum);
  }
  k_eposinit<<<(NN + 255) / 256, 256, 0, stream>>>(coff, epos);
  k_scatter<<<(EE + 255) / 256, 256, 0, stream>>>(dsts, epos, eid);
  k_sort<<<(NN + 255) / 256, 256, 0, stream>>>(coff, eid);
  k_wt<<<dim3(DD / 16, DB / 16, LL), 256, 0, stream>>>(cW1, bw1, DD, DB);
  k_wt<<<dim3(DB / 16, DD / 16, LL), 256, 0, stream>>>(cW2, bw2, DB, DD);
  k_wt<<<dim3(DD / 16, DD / 16, LL - 1), 256, 0, stream>>>(vW1, bvw1, DD, DD);
  k_wt<<<dim3(DD / 16, DD / 16, LL - 1), 256, 0, stream>>>(vW2, bvw2, DD, DD);

  for (int l = 0; l < LL; ++l) {
    int writePool = (l < LL - 1) ? 1 : 0;
    k_prep<<<(GG + 3) / 4, 256, 0, stream>>>(hb, vn, hvb, vtmpb, goff, writePool);
    k_aggr<<<(NN + 3) / 4, 256, 0, stream>>>(hvb, tbuf, srcs, eid, coff, ea,
                                             bondE + (size_t)l * 3 * 6 * DD, eps, l);
    k_mfma_gemm<<<dim3(MPAD / 128, DB / 128), 256, 0, stream>>>(
        tbuf, NN, DD, bw1 + (size_t)l * DB * DD, DB,
        c1b, 1, 1, cb1 + (size_t)l * DB, cbn1 + (size_t)l * 4 * DB);
    if (l < LL - 1) {
      k_mfma_gemm<<<dim3(MPAD / 128, DD / 128), 256, 0, stream>>>(
          c1b, NN, DB, bw2 + (size_t)l * DD * DB, DD,
          hb, 1, 1, cb2 + (size_t)l * DD, nbn + (size_t)l * 4 * DD);
      k_mfma_gemm<<<dim3(GG / 128, DD / 128), 256, 0, stream>>>(
          vtmpb, GG, DD, bvw1 + (size_t)l * DD * DD, DD,
          ub, 1, 1, vb1 + (size_t)l * DD, vbn1 + (size_t)l * 4 * DD);
      k_mfma_gemm<<<dim3(GG / 128, DD / 128), 256, 0, stream>>>(
          ub, GG, DD, bvw2 + (size_t)l * DD * DD, DD,
          vn, 0, 1, vb2 + (size_t)l * DD, vbn2 + (size_t)l * 4 * DD);
    } else {
      // final layer: f32 output straight to d_out (overwrites hvb region; hv dead here)
      k_mfma_gemm<<<dim3(MPAD / 128, DD / 128), 256, 0, stream>>>(
          c1b, NN, DB, bw2 + (size_t)l * DD * DB, DD,
          (float*)d_out, 0, 0, cb2 + (size_t)l * DD, nbn + (size_t)l * 4 * DD);
    }
  }
}

// Round 4
// 1153.649 us; speedup vs baseline: 1.3413x; 1.1886x over previous
//
#include <hip/hip_runtime.h>

#define NN 100000
#define EE 300000
#define DD 256
#define LL 5
#define GG 4096
#define DB 512
#define MPAD 100096   // 782*128

typedef __attribute__((ext_vector_type(4))) float f32x4;
typedef __attribute__((ext_vector_type(8))) short s16x8;

__device__ __forceinline__ ushort f2bf(float f) {
  unsigned u = __float_as_uint(f);
  return (ushort)((u + 0x7fffu + ((u >> 16) & 1u)) >> 16);
}
__device__ __forceinline__ float b2f(ushort u) {
  return __uint_as_float(((unsigned)u) << 16);
}

__device__ __forceinline__ void gload16(const void* g, void* l) {
  __builtin_amdgcn_global_load_lds((const __attribute__((address_space(1))) void*)g,
                                   (__attribute__((address_space(3))) void*)l, 16, 0, 0);
}

// ---------------- atom encoder: hb[n,:] = bf16( sum_f atom_emb[f, x[n,f], :] ) ----------
__global__ void k_atom(const int* __restrict__ x, const float* __restrict__ emb,
                       ushort* __restrict__ hb) {
  int n = blockIdx.x * 4 + (threadIdx.x >> 6);
  if (n >= NN) return;
  int d = (threadIdx.x & 63) * 4;
  float ax = 0.f, ay = 0.f, az = 0.f, aw = 0.f;
#pragma unroll
  for (int f = 0; f < 9; ++f) {
    int v = x[n * 9 + f];
    const float4 t = *(const float4*)&emb[((size_t)(f * 120 + v)) * DD + d];
    ax += t.x; ay += t.y; az += t.z; aw += t.w;
  }
  ushort4 o; o.x = f2bf(ax); o.y = f2bf(ay); o.z = f2bf(az); o.w = f2bf(aw);
  *(ushort4*)&hb[(size_t)n * DD + d] = o;
}

__global__ void k_vninit(const float* __restrict__ vn0, float* __restrict__ vn) {
  int i = blockIdx.x * blockDim.x + threadIdx.x;
  if (i < GG * DD) vn[i] = vn0[i & (DD - 1)];
}

__global__ void k_goff(const int* __restrict__ batch, int* __restrict__ goff) {
  int g = blockIdx.x * blockDim.x + threadIdx.x;
  if (g > GG) return;
  if (g == GG) { goff[GG] = NN; return; }
  int lo = 0, hi = NN;
  while (lo < hi) { int mid = (lo + hi) >> 1; if (batch[mid] < g) lo = mid + 1; else hi = mid; }
  goff[g] = lo;
}

__global__ void k_zero(int* __restrict__ p, int n) {
  int i = blockIdx.x * 256 + threadIdx.x;
  if (i < n) p[i] = 0;
}

__global__ void k_deg(const int* __restrict__ dst, int* __restrict__ deg) {
  int e = blockIdx.x * 256 + threadIdx.x;
  if (e < EE) atomicAdd(&deg[dst[e]], 1);
}

// ---------------- hierarchical scan ----------------
__global__ void k_scan1(const int* __restrict__ deg, int* __restrict__ coff,
                        int* __restrict__ bsum) {
  __shared__ int wsum[16];
  __shared__ int wpre[16];
  int lane = threadIdx.x & 63, wid = threadIdx.x >> 6;
  int i = blockIdx.x * 1024 + threadIdx.x;
  int v = (i < NN) ? deg[i] : 0;
  int xv = v;
#pragma unroll
  for (int off = 1; off < 64; off <<= 1) {
    int y = __shfl_up(xv, off);
    if (lane >= off) xv += y;
  }
  if (lane == 63) wsum[wid] = xv;
  __syncthreads();
  if (wid == 0 && lane < 16) {
    int s = wsum[lane];
    int xx = s;
#pragma unroll
    for (int off = 1; off < 16; off <<= 1) {
      int y = __shfl_up(xx, off);
      if (lane >= off) xx += y;
    }
    wpre[lane] = xx - s;
  }
  __syncthreads();
  int val = xv + wpre[wid];
  if (i < NN) coff[i + 1] = val;
  if (threadIdx.x == 1023) bsum[blockIdx.x] = val;
}

__global__ void k_scan2(int* __restrict__ bsum, int nb) {   // 1 block, 128 threads
  __shared__ int ws[2];
  int t = threadIdx.x, lane = t & 63, wid = t >> 6;
  int v = (t < nb) ? bsum[t] : 0;
  int xv = v;
#pragma unroll
  for (int off = 1; off < 64; off <<= 1) {
    int y = __shfl_up(xv, off);
    if (lane >= off) xv += y;
  }
  if (lane == 63) ws[wid] = xv;
  __syncthreads();
  int incl = xv + ((wid == 1) ? ws[0] : 0);
  if (t < nb) bsum[t] = incl - v;
}

__global__ void k_scan3(int* __restrict__ coff, const int* __restrict__ bpre) {
  int i = blockIdx.x * 1024 + threadIdx.x;
  if (i == 0) coff[0] = 0;
  if (i < NN) coff[i + 1] += bpre[i >> 10];
}

__global__ void k_eposinit(const int* __restrict__ coff, int* __restrict__ epos) {
  int n = blockIdx.x * 256 + threadIdx.x;
  if (n < NN) epos[n] = coff[n];
}

__global__ void k_scatter(const int* __restrict__ dst, int* __restrict__ epos,
                          int* __restrict__ eid) {
  int e = blockIdx.x * 256 + threadIdx.x;
  if (e < EE) { int p = atomicAdd(&epos[dst[e]], 1); eid[p] = e; }
}

__global__ void k_sort(const int* __restrict__ coff, int* __restrict__ eid) {
  int n = blockIdx.x * 256 + threadIdx.x;
  if (n >= NN) return;
  int s = coff[n], t = coff[n + 1];
  for (int i = s + 1; i < t; ++i) {
    int key = eid[i]; int j = i - 1;
    while (j >= s && eid[j] > key) { eid[j + 1] = eid[j]; --j; }
    eid[j + 1] = key;
  }
}

// ---------------- edge metadata in CSR order: emeta[idx] = src | combo<<17 --------------
__global__ void k_emeta(const int* __restrict__ eid, const int* __restrict__ srcs,
                        const int* __restrict__ eattr, unsigned* __restrict__ emeta) {
  int idx = blockIdx.x * 256 + threadIdx.x;
  if (idx >= EE) return;
  int e = eid[idx];
  int s = srcs[e];
  unsigned c = (unsigned)(eattr[e * 3 + 0] + 2 * eattr[e * 3 + 1] + 4 * eattr[e * 3 + 2]);
  emeta[idx] = (unsigned)s | (c << 17);
}

// ---------------- bond8[l][c][:] = sum_f bondE[l][f][bit_f(c)][:] -----------------------
__global__ void k_bond8(const float* __restrict__ bondE, float* __restrict__ bond8) {
  int l = blockIdx.x, c = blockIdx.y, d = threadIdx.x;   // 256 threads
  float v = bondE[(((size_t)l * 3 + 0) * 6 + (c & 1)) * DD + d]
          + bondE[(((size_t)l * 3 + 1) * 6 + ((c >> 1) & 1)) * DD + d]
          + bondE[(((size_t)l * 3 + 2) * 6 + ((c >> 2) & 1)) * DD + d];
  bond8[((size_t)l * 8 + c) * DD + d] = v;
}

// ---------------- weight transpose + bf16: [L][K][N] f32 -> [L][N][K] bf16 --------------
__global__ void k_wt(const float* __restrict__ in, ushort* __restrict__ out, int K, int N) {
  __shared__ float t[16][17];
  int l = blockIdx.z;
  int kb = blockIdx.x * 16, nb = blockIdx.y * 16;
  int tx = threadIdx.x & 15, ty = threadIdx.x >> 4;
  t[ty][tx] = in[(size_t)l * K * N + (size_t)(kb + ty) * N + nb + tx];
  __syncthreads();
  out[(size_t)l * N * K + (size_t)(nb + ty) * K + kb + tx] = f2bf(t[tx][ty]);
}

// ---------------- prep: hv[n]=hb[n]+vn[g] (bf16); pool: vtemp[g]=sum(hv)+vn[g] ----------
__global__ void k_prep(const ushort* __restrict__ hb, const float* __restrict__ vn,
                       ushort* __restrict__ hvb, ushort* __restrict__ vtempb,
                       const int* __restrict__ goff, int writePool) {
  int g = blockIdx.x * 4 + (threadIdx.x >> 6);
  if (g >= GG) return;
  int d = (threadIdx.x & 63) * 4;
  float4 v = *(const float4*)&vn[(size_t)g * DD + d];
  float ax = v.x, ay = v.y, az = v.z, aw = v.w;
  int r0 = goff[g], r1 = goff[g + 1];
  for (int r = r0; r < r1; ++r) {
    ushort4 hu = *(const ushort4*)&hb[(size_t)r * DD + d];
    float h0 = b2f(hu.x) + v.x, h1 = b2f(hu.y) + v.y;
    float h2 = b2f(hu.z) + v.z, h3 = b2f(hu.w) + v.w;
    ushort4 o; o.x = f2bf(h0); o.y = f2bf(h1); o.z = f2bf(h2); o.w = f2bf(h3);
    *(ushort4*)&hvb[(size_t)r * DD + d] = o;
    ax += h0; ay += h1; az += h2; aw += h3;
  }
  if (writePool) {
    ushort4 o; o.x = f2bf(ax); o.y = f2bf(ay); o.z = f2bf(az); o.w = f2bf(aw);
    *(ushort4*)&vtempb[(size_t)g * DD + d] = o;
  }
}

// ---------------- aggregate: t[n] = (1+eps)hv[n] + sum relu(hv[src]+bond8[c]) -----------
__global__ void k_aggr(const ushort* __restrict__ hvb, ushort* __restrict__ tb,
                       const unsigned* __restrict__ emeta, const int* __restrict__ coff,
                       const float* __restrict__ bond8l, const float* __restrict__ epsp,
                       int l) {
  int n = blockIdx.x * 4 + (threadIdx.x >> 6);
  if (n >= NN) return;
  int d = (threadIdx.x & 63) * 4;
  float ax = 0.f, ay = 0.f, az = 0.f, aw = 0.f;
  int s0 = coff[n], s1 = coff[n + 1];
  int idx = s0;
  for (; idx + 2 <= s1; idx += 2) {
    unsigned m0 = emeta[idx], m1 = emeta[idx + 1];
    const ushort4 h0 = *(const ushort4*)&hvb[(size_t)(m0 & 0x1FFFFu) * DD + d];
    const ushort4 h1 = *(const ushort4*)&hvb[(size_t)(m1 & 0x1FFFFu) * DD + d];
    const float4 b0 = *(const float4*)&bond8l[(size_t)(m0 >> 17) * DD + d];
    const float4 b1 = *(const float4*)&bond8l[(size_t)(m1 >> 17) * DD + d];
    ax += fmaxf(b2f(h0.x) + b0.x, 0.f) + fmaxf(b2f(h1.x) + b1.x, 0.f);
    ay += fmaxf(b2f(h0.y) + b0.y, 0.f) + fmaxf(b2f(h1.y) + b1.y, 0.f);
    az += fmaxf(b2f(h0.z) + b0.z, 0.f) + fmaxf(b2f(h1.z) + b1.z, 0.f);
    aw += fmaxf(b2f(h0.w) + b0.w, 0.f) + fmaxf(b2f(h1.w) + b1.w, 0.f);
  }
  if (idx < s1) {
    unsigned m0 = emeta[idx];
    const ushort4 h0 = *(const ushort4*)&hvb[(size_t)(m0 & 0x1FFFFu) * DD + d];
    const float4 b0 = *(const float4*)&bond8l[(size_t)(m0 >> 17) * DD + d];
    ax += fmaxf(b2f(h0.x) + b0.x, 0.f);
    ay += fmaxf(b2f(h0.y) + b0.y, 0.f);
    az += fmaxf(b2f(h0.z) + b0.z, 0.f);
    aw += fmaxf(b2f(h0.w) + b0.w, 0.f);
  }
  float ep = 1.f + epsp[l];
  const ushort4 hn = *(const ushort4*)&hvb[(size_t)n * DD + d];
  ushort4 o;
  o.x = f2bf(ep * b2f(hn.x) + ax); o.y = f2bf(ep * b2f(hn.y) + ay);
  o.z = f2bf(ep * b2f(hn.z) + az); o.w = f2bf(ep * b2f(hn.w) + aw);
  *(ushort4*)&tb[(size_t)n * DD + d] = o;
}

// ---------------- bf16 MFMA GEMM, 128x128 tile, 2-phase dbuf, fused bias/BN(/relu) ------
__global__ __launch_bounds__(256) void k_mfma_gemm(
    const ushort* __restrict__ A, int M, int K,
    const ushort* __restrict__ BT, int N,
    void* __restrict__ Cv, int outBf16, int doRelu,
    const float* __restrict__ bias, const float* __restrict__ bn) {
  __shared__ ushort Asm[2][128 * 32];
  __shared__ ushort Bsm[2][128 * 32];
  const int tid = threadIdx.x;
  const int lane = tid & 63;
  const int w = tid >> 6;
  const int rowBase = blockIdx.x * 128;
  const int colBase = blockIdx.y * 128;
  const int wrow = (w >> 1) * 64, wcol = (w & 1) * 64;
  const int r16 = lane & 15, kgrp = lane >> 4;

  f32x4 acc[4][4];
#pragma unroll
  for (int m = 0; m < 4; ++m)
#pragma unroll
    for (int n = 0; n < 4; ++n) acc[m][n] = (f32x4)0.f;

  const int ca0 = tid, ca1 = tid + 256;
  const int ra0 = ca0 >> 2, ka0 = (ca0 & 3) ^ ((ra0 >> 1) & 3);
  const int ra1 = ca1 >> 2, ka1 = (ca1 & 3) ^ ((ra1 >> 1) & 3);
  const ushort* Ap0 = A + (size_t)(rowBase + ra0) * K + ka0 * 8;
  const ushort* Ap1 = A + (size_t)(rowBase + ra1) * K + ka1 * 8;
  const ushort* Bp0 = BT + (size_t)(colBase + ra0) * K + ka0 * 8;
  const ushort* Bp1 = BT + (size_t)(colBase + ra1) * K + ka1 * 8;

  int aoff[4], boff[4];
#pragma unroll
  for (int m = 0; m < 4; ++m) {
    int row = wrow + m * 16 + r16;
    aoff[m] = row * 64 + ((kgrp ^ ((row >> 1) & 3)) << 4);
    int col = wcol + m * 16 + r16;
    boff[m] = col * 64 + ((kgrp ^ ((col >> 1) & 3)) << 4);
  }

  const int nk = K >> 5;
  gload16(Ap0, (char*)Asm + ca0 * 16);
  gload16(Ap1, (char*)Asm + ca1 * 16);
  gload16(Bp0, (char*)Bsm + ca0 * 16);
  gload16(Bp1, (char*)Bsm + ca1 * 16);
  __syncthreads();

  int cur = 0;
  for (int t = 0; t < nk; ++t) {
    int nxt = cur ^ 1;
    if (t + 1 < nk) {
      int ko = (t + 1) << 5;
      gload16(Ap0 + ko, (char*)Asm + nxt * 8192 + ca0 * 16);
      gload16(Ap1 + ko, (char*)Asm + nxt * 8192 + ca1 * 16);
      gload16(Bp0 + ko, (char*)Bsm + nxt * 8192 + ca0 * 16);
      gload16(Bp1 + ko, (char*)Bsm + nxt * 8192 + ca1 * 16);
    }
    const char* cA = (const char*)Asm + cur * 8192;
    const char* cB = (const char*)Bsm + cur * 8192;
    s16x8 a[4], b[4];
#pragma unroll
    for (int m = 0; m < 4; ++m) a[m] = *(const s16x8*)(cA + aoff[m]);
#pragma unroll
    for (int n = 0; n < 4; ++n) b[n] = *(const s16x8*)(cB + boff[n]);
#pragma unroll
    for (int m = 0; m < 4; ++m)
#pragma unroll
      for (int n = 0; n < 4; ++n)
        acc[m][n] = __builtin_amdgcn_mfma_f32_16x16x32_bf16(a[m], b[n], acc[m][n], 0, 0, 0);
    __syncthreads();
    cur = nxt;
  }

  float alpha[4], beta[4];
#pragma unroll
  for (int n = 0; n < 4; ++n) {
    int col = colBase + wcol + n * 16 + r16;
    float g = bn[col], bb = bn[N + col], mm = bn[2 * N + col], vv = bn[3 * N + col];
    float s = g * rsqrtf(vv + 1e-5f);
    alpha[n] = s; beta[n] = fmaf(bias[col] - mm, s, bb);
  }
#pragma unroll
  for (int m = 0; m < 4; ++m) {
#pragma unroll
    for (int r = 0; r < 4; ++r) {
      int row = rowBase + wrow + m * 16 + kgrp * 4 + r;
      if (row < M) {
#pragma unroll
        for (int n = 0; n < 4; ++n) {
          int col = colBase + wcol + n * 16 + r16;
          float v = fmaf(acc[m][n][r], alpha[n], beta[n]);
          if (doRelu) v = fmaxf(v, 0.f);
          if (outBf16) ((ushort*)Cv)[(size_t)row * N + col] = f2bf(v);
          else         ((float*)Cv)[(size_t)row * N + col] = v;
        }
      }
    }
  }
}

extern "C" void kernel_launch(void* const* d_in, const int* in_sizes, int n_in,
                              void* d_out, int out_size, void* d_ws, size_t ws_size,
                              hipStream_t stream) {
  const int*   x     = (const int*)d_in[0];
  const int*   ei    = (const int*)d_in[1];
  const int*   ea    = (const int*)d_in[2];
  const int*   batch = (const int*)d_in[3];
  const float* atomE = (const float*)d_in[4];
  const float* bondE = (const float*)d_in[5];
  const float* vn0   = (const float*)d_in[6];
  const float* eps   = (const float*)d_in[7];
  const float* cW1   = (const float*)d_in[8];
  const float* cb1   = (const float*)d_in[9];
  const float* cbn1  = (const float*)d_in[10];
  const float* cW2   = (const float*)d_in[11];
  const float* cb2   = (const float*)d_in[12];
  const float* nbn   = (const float*)d_in[13];
  const float* vW1   = (const float*)d_in[14];
  const float* vb1   = (const float*)d_in[15];
  const float* vbn1  = (const float*)d_in[16];
  const float* vW2   = (const float*)d_in[17];
  const float* vb2   = (const float*)d_in[18];
  const float* vbn2  = (const float*)d_in[19];
  (void)in_sizes; (void)n_in; (void)out_size; (void)ws_size;

  char* wsp = (char*)d_ws;
  size_t o = 0;
  auto alloc = [&](size_t bytes) -> char* {
    char* p = wsp + o; o += (bytes + 255) & ~(size_t)255; return p;
  };
  ushort* tbuf  = (ushort*)alloc((size_t)MPAD * DD * 2);
  ushort* c1b   = (ushort*)alloc((size_t)MPAD * DB * 2);
  ushort* hb    = (ushort*)alloc((size_t)NN * DD * 2);
  float*  vn    = (float*) alloc((size_t)GG * DD * 4);
  ushort* vtmpb = (ushort*)alloc((size_t)GG * DD * 2);
  ushort* ub    = (ushort*)alloc((size_t)GG * DD * 2);
  ushort* bw1   = (ushort*)alloc((size_t)LL * DB * DD * 2);
  ushort* bw2   = (ushort*)alloc((size_t)LL * DD * DB * 2);
  ushort* bvw1  = (ushort*)alloc((size_t)(LL - 1) * DD * DD * 2);
  ushort* bvw2  = (ushort*)alloc((size_t)(LL - 1) * DD * DD * 2);
  float*  bond8 = (float*) alloc((size_t)LL * 8 * DD * 4);
  unsigned* emeta = (unsigned*)alloc((size_t)EE * 4);
  int* coff = (int*)alloc((size_t)(NN + 1) * 4);
  int* deg  = (int*)alloc((size_t)NN * 4);
  int* epos = (int*)alloc((size_t)NN * 4);
  int* eid  = (int*)alloc((size_t)EE * 4);
  int* goff = (int*)alloc((size_t)(GG + 1) * 4);
  int* bsum = (int*)alloc((size_t)128 * 4);

  const int* srcs = ei;
  const int* dsts = ei + EE;
  ushort* hvb = (ushort*)d_out;   // bf16 hv in d_out low half; dead before final f32 write

  // ---- one-time per call ----
  k_atom<<<(NN + 3) / 4, 256, 0, stream>>>(x, atomE, hb);
  k_vninit<<<(GG * DD + 255) / 256, 256, 0, stream>>>(vn0, vn);
  k_goff<<<(GG + 256) / 256, 256, 0, stream>>>(batch, goff);
  k_zero<<<(NN + 255) / 256, 256, 0, stream>>>(deg, NN);
  k_deg<<<(EE + 255) / 256, 256, 0, stream>>>(dsts, deg);
  {
    int nb = (NN + 1023) / 1024;   // 98
    k_scan1<<<nb, 1024, 0, stream>>>(deg, coff, bsum);
    k_scan2<<<1, 128, 0, stream>>>(bsum, nb);
    k_scan3<<<nb, 1024, 0, stream>>>(coff, bsum);
  }
  k_eposinit<<<(NN + 255) / 256, 256, 0, stream>>>(coff, epos);
  k_scatter<<<(EE + 255) / 256, 256, 0, stream>>>(dsts, epos, eid);
  k_sort<<<(NN + 255) / 256, 256, 0, stream>>>(coff, eid);
  k_emeta<<<(EE + 255) / 256, 256, 0, stream>>>(eid, srcs, ea, emeta);
  k_bond8<<<dim3(LL, 8), 256, 0, stream>>>(bondE, bond8);
  k_wt<<<dim3(DD / 16, DB / 16, LL), 256, 0, stream>>>(cW1, bw1, DD, DB);
  k_wt<<<dim3(DB / 16, DD / 16, LL), 256, 0, stream>>>(cW2, bw2, DB, DD);
  k_wt<<<dim3(DD / 16, DD / 16, LL - 1), 256, 0, stream>>>(vW1, bvw1, DD, DD);
  k_wt<<<dim3(DD / 16, DD / 16, LL - 1), 256, 0, stream>>>(vW2, bvw2, DD, DD);

  for (int l = 0; l < LL; ++l) {
    int writePool = (l < LL - 1) ? 1 : 0;
    k_prep<<<(GG + 3) / 4, 256, 0, stream>>>(hb, vn, hvb, vtmpb, goff, writePool);
    k_aggr<<<(NN + 3) / 4, 256, 0, stream>>>(hvb, tbuf, emeta, coff,
                                             bond8 + (size_t)l * 8 * DD, eps, l);
    k_mfma_gemm<<<dim3(MPAD / 128, DB / 128), 256, 0, stream>>>(
        tbuf, NN, DD, bw1 + (size_t)l * DB * DD, DB,
        c1b, 1, 1, cb1 + (size_t)l * DB, cbn1 + (size_t)l * 4 * DB);
    if (l < LL - 1) {
      k_mfma_gemm<<<dim3(MPAD / 128, DD / 128), 256, 0, stream>>>(
          c1b, NN, DB, bw2 + (size_t)l * DD * DB, DD,
          hb, 1, 1, cb2 + (size_t)l * DD, nbn + (size_t)l * 4 * DD);
      k_mfma_gemm<<<dim3(GG / 128, DD / 128), 256, 0, stream>>>(
          vtmpb, GG, DD, bvw1 + (size_t)l * DD * DD, DD,
          ub, 1, 1, vb1 + (size_t)l * DD, vbn1 + (size_t)l * 4 * DD);
      k_mfma_gemm<<<dim3(GG / 128, DD / 128), 256, 0, stream>>>(
          ub, GG, DD, bvw2 + (size_t)l * DD * DD, DD,
          vn, 0, 1, vb2 + (size_t)l * DD, vbn2 + (size_t)l * 4 * DD);
    } else {
      k_mfma_gemm<<<dim3(MPAD / 128, DD / 128), 256, 0, stream>>>(
          c1b, NN, DB, bw2 + (size_t)l * DD * DB, DD,
          (float*)d_out, 0, 0, cb2 + (size_t)l * DD, nbn + (size_t)l * 4 * DD);
    }
  }
}